// Round 1
// baseline (1024.589 us; speedup 1.0000x reference)
//
#include <hip/hip_runtime.h>

#define NVERT 6890
#define NJNT  24
#define NBETA 10
#define NPOSE 207
#define NBATCH 512

__constant__ int c_par[NJNT] = {-1,0,0,0,1,2,3,4,5,6,7,8,9,9,9,12,13,14,16,17,18,19,20,21};

// ---- Kernel A: Jbase[72] = Jr@v_template, Jdirs[72*10] = Jr@shapedirs ----
__global__ __launch_bounds__(256) void k_jreg(
    const float* __restrict__ Jr, const float* __restrict__ vt,
    const float* __restrict__ sd, float* __restrict__ wsJ) {
  const int jc = blockIdx.x;            // 0..71 = j*3+c
  const int j = jc / 3, c = jc % 3;
  const int tid = threadIdx.x;
  float acc[11];
  #pragma unroll
  for (int k = 0; k < 11; ++k) acc[k] = 0.f;
  for (int v = tid; v < NVERT; v += 256) {
    const float w = Jr[j * NVERT + v];
    acc[0] += w * vt[v * 3 + c];
    const float* s = sd + v * 30 + c * 10;
    #pragma unroll
    for (int k = 0; k < 10; ++k) acc[1 + k] += w * s[k];
  }
  #pragma unroll
  for (int off = 32; off > 0; off >>= 1) {
    #pragma unroll
    for (int k = 0; k < 11; ++k) acc[k] += __shfl_down(acc[k], off, 64);
  }
  __shared__ float red[4][11];
  const int lane = tid & 63, wv = tid >> 6;
  if (lane == 0) {
    #pragma unroll
    for (int k = 0; k < 11; ++k) red[wv][k] = acc[k];
  }
  __syncthreads();
  if (tid == 0) {
    #pragma unroll
    for (int k = 0; k < 11; ++k) {
      const float s = red[0][k] + red[1][k] + red[2][k] + red[3][k];
      if (k == 0) wsJ[jc] = s;
      else        wsJ[72 + jc * 10 + (k - 1)] = s;
    }
  }
}

// ---- Kernel B: one thread per batch: J(beta), Rodrigues, chain, G, lrotmin ----
__global__ __launch_bounds__(64) void k_chain(
    const float* __restrict__ betas, const float* __restrict__ thetas,
    const float* __restrict__ scale, const float* __restrict__ wsJ,
    float* __restrict__ wsG, float* __restrict__ wsL) {
  const int b = blockIdx.x * 64 + threadIdx.x;
  float be[NBETA];
  #pragma unroll
  for (int s = 0; s < NBETA; ++s) be[s] = betas[b * NBETA + s];
  float J[NJNT][3];
  for (int j = 0; j < NJNT; ++j) {
    #pragma unroll
    for (int c = 0; c < 3; ++c) {
      float a = wsJ[j * 3 + c];
      const float* d = wsJ + 72 + (j * 3 + c) * 10;
      #pragma unroll
      for (int s = 0; s < NBETA; ++s) a += d[s] * be[s];
      J[j][c] = a;
    }
  }
  const float sc = scale[0];
  float M[NJNT][12];                     // running chain transforms (3x4)
  float* Gb = wsG + (size_t)b * 288;
  float* Lb = wsL + (size_t)b * NPOSE;
  for (int i = 0; i < NJNT; ++i) {
    const float rx = thetas[b * 72 + i * 3 + 0];
    const float ry = thetas[b * 72 + i * 3 + 1];
    const float rz = thetas[b * 72 + i * 3 + 2];
    const float th = sqrtf(rx * rx + ry * ry + rz * rz) + 1e-8f;
    const float inv = 1.f / th;
    const float x = rx * inv, y = ry * inv, z = rz * inv;
    const float cs = cosf(th), sn = sinf(th), omc = 1.f - cs;
    float R[9];
    R[0] = cs + omc * x * x;     R[1] = omc * x * y - sn * z; R[2] = omc * x * z + sn * y;
    R[3] = omc * x * y + sn * z; R[4] = cs + omc * y * y;     R[5] = omc * y * z - sn * x;
    R[6] = omc * x * z - sn * y; R[7] = omc * y * z + sn * x; R[8] = cs + omc * z * z;
    if (i == 0) {
      #pragma unroll
      for (int k = 0; k < 9; ++k) R[k] *= sc;       // root scaled
    } else {
      #pragma unroll
      for (int k = 0; k < 9; ++k)                   // lrotmin (root excluded)
        Lb[(i - 1) * 9 + k] = R[k] - ((k == 0 || k == 4 || k == 8) ? 1.f : 0.f);
    }
    if (i == 0) {
      #pragma unroll
      for (int r = 0; r < 3; ++r) {
        M[0][r*4+0] = R[r*3+0]; M[0][r*4+1] = R[r*3+1];
        M[0][r*4+2] = R[r*3+2]; M[0][r*4+3] = J[0][r];
      }
    } else {
      const int p = c_par[i];
      const float t0 = J[i][0] - J[p][0];
      const float t1 = J[i][1] - J[p][1];
      const float t2 = J[i][2] - J[p][2];
      for (int r = 0; r < 3; ++r) {
        const float p0 = M[p][r*4+0], p1 = M[p][r*4+1], p2 = M[p][r*4+2], p3 = M[p][r*4+3];
        M[i][r*4+0] = p0*R[0] + p1*R[3] + p2*R[6];
        M[i][r*4+1] = p0*R[1] + p1*R[4] + p2*R[7];
        M[i][r*4+2] = p0*R[2] + p1*R[5] + p2*R[8];
        M[i][r*4+3] = p0*t0 + p1*t1 + p2*t2 + p3;
      }
    }
    #pragma unroll
    for (int r = 0; r < 3; ++r) {                    // G = M with t -= R@J[i]
      Gb[i*12 + r*4 + 0] = M[i][r*4+0];
      Gb[i*12 + r*4 + 1] = M[i][r*4+1];
      Gb[i*12 + r*4 + 2] = M[i][r*4+2];
      Gb[i*12 + r*4 + 3] = M[i][r*4+3]
          - (M[i][r*4+0]*J[i][0] + M[i][r*4+1]*J[i][1] + M[i][r*4+2]*J[i][2]);
    }
  }
}

// ---- Kernel C: shape blend + pose blend + LBS. block = 256 vertices x 8 batches ----
__global__ __launch_bounds__(256) void k_skin(
    const float* __restrict__ betas, const float* __restrict__ trans,
    const float* __restrict__ vtpl, const float* __restrict__ sd,
    const float* __restrict__ pdir, const float* __restrict__ wgt,
    const float* __restrict__ wsG, const float* __restrict__ wsL,
    float* __restrict__ out) {
  __shared__ float sL[8 * NPOSE];   // 1656 floats
  __shared__ float sG[8 * 288];     // 2304 floats
  __shared__ float sB[8 * NBETA];   // 80
  __shared__ float sT[8 * 3];       // 24
  const int tid = threadIdx.x;
  const int b0 = blockIdx.y * 8;
  for (int i = tid; i < 8 * NPOSE; i += 256) sL[i] = wsL[(size_t)b0 * NPOSE + i];
  for (int i = tid; i < 8 * 288;   i += 256) sG[i] = wsG[(size_t)b0 * 288 + i];
  if (tid < 80) sB[tid] = betas[b0 * NBETA + tid];
  if (tid < 24) sT[tid] = trans[b0 * 3 + tid];
  __syncthreads();
  const int v = blockIdx.x * 256 + tid;
  if (v >= NVERT) return;

  float vp[8][3];
  {
    float sdv[30];
    #pragma unroll
    for (int k = 0; k < 30; ++k) sdv[k] = sd[v * 30 + k];
    const float vt0 = vtpl[v*3+0], vt1 = vtpl[v*3+1], vt2 = vtpl[v*3+2];
    #pragma unroll
    for (int bb = 0; bb < 8; ++bb) {
      float a0 = vt0, a1 = vt1, a2 = vt2;
      #pragma unroll
      for (int s = 0; s < NBETA; ++s) {
        const float bv = sB[bb*NBETA+s];
        a0 += bv * sdv[s]; a1 += bv * sdv[10+s]; a2 += bv * sdv[20+s];
      }
      vp[bb][0]=a0; vp[bb][1]=a1; vp[bb][2]=a2;
    }
  }
  // pose blend: vp += lrotmin . posedirs[v]
  const float* pv = pdir + (size_t)v * 621;
  for (int p = 0; p < NPOSE; ++p) {
    const float d0 = pv[p], d1 = pv[NPOSE + p], d2 = pv[2*NPOSE + p];
    #pragma unroll
    for (int bb = 0; bb < 8; ++bb) {
      const float l = sL[bb*NPOSE + p];
      vp[bb][0] += l*d0; vp[bb][1] += l*d1; vp[bb][2] += l*d2;
    }
  }
  // LBS
  float w[NJNT];
  #pragma unroll
  for (int j = 0; j < NJNT; ++j) w[j] = wgt[v*NJNT + j];
  for (int bb = 0; bb < 8; ++bb) {
    const float* g = sG + bb*288;
    float T[12];
    #pragma unroll
    for (int k = 0; k < 12; ++k) T[k] = 0.f;
    for (int j = 0; j < NJNT; ++j) {
      const float wj = w[j];
      #pragma unroll
      for (int k = 0; k < 12; ++k) T[k] += wj * g[j*12+k];
    }
    const float x = vp[bb][0], y = vp[bb][1], z = vp[bb][2];
    float* o = out + ((size_t)(b0+bb)*NVERT + v)*3;
    o[0] = T[0]*x + T[1]*y + T[2]*z  + T[3]  + sT[bb*3+0];
    o[1] = T[4]*x + T[5]*y + T[6]*z  + T[7]  + sT[bb*3+1];
    o[2] = T[8]*x + T[9]*y + T[10]*z + T[11] + sT[bb*3+2];
  }
}

// ---- Kernel D: joints = Jr @ result, one block per batch, wave-per-6-joints ----
__global__ __launch_bounds__(256) void k_joints(
    const float* __restrict__ Jr, const float* __restrict__ res,
    float* __restrict__ joints) {
  const int b = blockIdx.x;
  const int lane = threadIdx.x & 63, wv = threadIdx.x >> 6;
  float acc[18];
  #pragma unroll
  for (int k = 0; k < 18; ++k) acc[k] = 0.f;
  const float* rb = res + (size_t)b * NVERT * 3;
  for (int v = lane; v < NVERT; v += 64) {
    const float r0 = rb[v*3+0], r1 = rb[v*3+1], r2 = rb[v*3+2];
    #pragma unroll
    for (int k = 0; k < 6; ++k) {
      const int j = wv + 4*k;
      const float w = Jr[j*NVERT + v];
      acc[k*3+0] += w*r0; acc[k*3+1] += w*r1; acc[k*3+2] += w*r2;
    }
  }
  #pragma unroll
  for (int off = 32; off > 0; off >>= 1) {
    #pragma unroll
    for (int k = 0; k < 18; ++k) acc[k] += __shfl_down(acc[k], off, 64);
  }
  if (lane == 0) {
    #pragma unroll
    for (int k = 0; k < 6; ++k) {
      const int j = wv + 4*k;
      joints[(size_t)b*72 + j*3 + 0] = acc[k*3+0];
      joints[(size_t)b*72 + j*3 + 1] = acc[k*3+1];
      joints[(size_t)b*72 + j*3 + 2] = acc[k*3+2];
    }
  }
}

extern "C" void kernel_launch(void* const* d_in, const int* in_sizes, int n_in,
                              void* d_out, int out_size, void* d_ws, size_t ws_size,
                              hipStream_t stream) {
  const float* betas  = (const float*)d_in[0];
  const float* thetas = (const float*)d_in[1];
  const float* trans  = (const float*)d_in[2];
  const float* scale  = (const float*)d_in[3];
  const float* vtpl   = (const float*)d_in[4];
  const float* sd     = (const float*)d_in[5];
  const float* pdir   = (const float*)d_in[6];
  const float* Jr     = (const float*)d_in[7];
  const float* wgt    = (const float*)d_in[8];
  float* out = (float*)d_out;

  float* ws  = (float*)d_ws;
  float* wsJ = ws;                         // 72 + 720 floats
  float* wsG = ws + 792;                   // 512*288 = 147456 floats
  float* wsL = wsG + (size_t)NBATCH * 288; // 512*207 = 105984 floats

  k_jreg <<<72, 256, 0, stream>>>(Jr, vtpl, sd, wsJ);
  k_chain<<<NBATCH/64, 64, 0, stream>>>(betas, thetas, scale, wsJ, wsG, wsL);
  k_skin <<<dim3((NVERT + 255)/256, NBATCH/8), 256, 0, stream>>>(
      betas, trans, vtpl, sd, pdir, wgt, wsG, wsL, out);
  k_joints<<<NBATCH, 256, 0, stream>>>(Jr, out, out + (size_t)NBATCH * NVERT * 3);
}

// Round 2
// 518.779 us; speedup vs baseline: 1.9750x; 1.9750x over previous
//
#include <hip/hip_runtime.h>

#define NVERT 6890
#define NJNT  24
#define NBETA 10
#define NPOSE 207
#define NBATCH 512
#define SPITCH 20672   // padded 20670 (=NVERT*3) to multiple of 32

__constant__ int c_par[NJNT] = {-1,0,0,0,1,2,3,4,5,6,7,8,9,9,9,12,13,14,16,17,18,19,20,21};

// ---- transpose posedirs [20670][207] -> pdirT [207][20672] (zero-padded) ----
__global__ __launch_bounds__(256) void k_tpose(const float* __restrict__ in,
                                               float* __restrict__ outT) {
  __shared__ float t[32][33];
  const int vc0 = blockIdx.x * 32, p0 = blockIdx.y * 32;
  const int tx = threadIdx.x, ty = threadIdx.y;  // 32 x 8
  for (int r = ty; r < 32; r += 8) {
    const int vc = vc0 + r, p = p0 + tx;
    t[r][tx] = (vc < NVERT * 3 && p < NPOSE) ? in[(size_t)vc * NPOSE + p] : 0.f;
  }
  __syncthreads();
  for (int r = ty; r < 32; r += 8) {
    const int p = p0 + r, vc = vc0 + tx;
    if (p < NPOSE) outT[(size_t)p * SPITCH + vc] = t[tx][r];
  }
}

// ---- Jreg stage 1: partial sums over 8 vertex chunks ----
__global__ __launch_bounds__(256) void k_jreg1(
    const float* __restrict__ Jr, const float* __restrict__ vt,
    const float* __restrict__ sd, float* __restrict__ wsJP) {
  const int jc = blockIdx.x, j = jc / 3, c = jc % 3;
  const int v0 = blockIdx.y * 864;
  const int vend = min(NVERT, v0 + 864);
  const int tid = threadIdx.x;
  float acc[11];
  #pragma unroll
  for (int k = 0; k < 11; ++k) acc[k] = 0.f;
  for (int v = v0 + tid; v < vend; v += 256) {
    const float w = Jr[j * NVERT + v];
    acc[0] += w * vt[v * 3 + c];
    const float* s = sd + (size_t)v * 30 + c * 10;
    #pragma unroll
    for (int k = 0; k < 10; ++k) acc[1 + k] += w * s[k];
  }
  #pragma unroll
  for (int off = 32; off > 0; off >>= 1) {
    #pragma unroll
    for (int k = 0; k < 11; ++k) acc[k] += __shfl_down(acc[k], off, 64);
  }
  __shared__ float red[4][11];
  const int lane = tid & 63, wv = tid >> 6;
  if (lane == 0) {
    #pragma unroll
    for (int k = 0; k < 11; ++k) red[wv][k] = acc[k];
  }
  __syncthreads();
  if (tid == 0) {
    #pragma unroll
    for (int k = 0; k < 11; ++k)
      wsJP[(size_t)(blockIdx.y * 72 + jc) * 11 + k] =
          red[0][k] + red[1][k] + red[2][k] + red[3][k];
  }
}

// ---- Jreg stage 2: reduce 8 partials ----
__global__ __launch_bounds__(128) void k_jreg2(const float* __restrict__ wsJP,
                                               float* __restrict__ wsJ) {
  const int jc = threadIdx.x;
  if (jc >= 72) return;
  #pragma unroll
  for (int k = 0; k < 11; ++k) {
    float s = 0.f;
    #pragma unroll
    for (int c8 = 0; c8 < 8; ++c8) s += wsJP[(size_t)(c8 * 72 + jc) * 11 + k];
    if (k == 0) wsJ[jc] = s;
    else        wsJ[72 + jc * 10 + (k - 1)] = s;
  }
}

// ---- chain: one thread per batch -> G [b][24][12], lrotmin transposed [207][512] ----
__global__ __launch_bounds__(64) void k_chain(
    const float* __restrict__ betas, const float* __restrict__ thetas,
    const float* __restrict__ scale, const float* __restrict__ wsJ,
    float* __restrict__ wsG, float* __restrict__ wsLT) {
  const int b = blockIdx.x * 64 + threadIdx.x;
  float be[NBETA];
  #pragma unroll
  for (int s = 0; s < NBETA; ++s) be[s] = betas[b * NBETA + s];
  float J[NJNT][3];
  for (int j = 0; j < NJNT; ++j) {
    #pragma unroll
    for (int c = 0; c < 3; ++c) {
      float a = wsJ[j * 3 + c];
      const float* d = wsJ + 72 + (j * 3 + c) * 10;
      #pragma unroll
      for (int s = 0; s < NBETA; ++s) a += d[s] * be[s];
      J[j][c] = a;
    }
  }
  const float sc = scale[0];
  float M[NJNT][12];
  float* Gb = wsG + (size_t)b * 288;
  for (int i = 0; i < NJNT; ++i) {
    const float rx = thetas[b * 72 + i * 3 + 0];
    const float ry = thetas[b * 72 + i * 3 + 1];
    const float rz = thetas[b * 72 + i * 3 + 2];
    const float th = sqrtf(rx * rx + ry * ry + rz * rz) + 1e-8f;
    const float inv = 1.f / th;
    const float x = rx * inv, y = ry * inv, z = rz * inv;
    const float cs = cosf(th), sn = sinf(th), omc = 1.f - cs;
    float R[9];
    R[0] = cs + omc * x * x;     R[1] = omc * x * y - sn * z; R[2] = omc * x * z + sn * y;
    R[3] = omc * x * y + sn * z; R[4] = cs + omc * y * y;     R[5] = omc * y * z - sn * x;
    R[6] = omc * x * z - sn * y; R[7] = omc * y * z + sn * x; R[8] = cs + omc * z * z;
    if (i == 0) {
      #pragma unroll
      for (int k = 0; k < 9; ++k) R[k] *= sc;
    } else {
      #pragma unroll
      for (int k = 0; k < 9; ++k)
        wsLT[(size_t)((i - 1) * 9 + k) * NBATCH + b] =
            R[k] - ((k == 0 || k == 4 || k == 8) ? 1.f : 0.f);
    }
    if (i == 0) {
      #pragma unroll
      for (int r = 0; r < 3; ++r) {
        M[0][r*4+0] = R[r*3+0]; M[0][r*4+1] = R[r*3+1];
        M[0][r*4+2] = R[r*3+2]; M[0][r*4+3] = J[0][r];
      }
    } else {
      const int p = c_par[i];
      const float t0 = J[i][0] - J[p][0];
      const float t1 = J[i][1] - J[p][1];
      const float t2 = J[i][2] - J[p][2];
      for (int r = 0; r < 3; ++r) {
        const float p0 = M[p][r*4+0], p1 = M[p][r*4+1], p2 = M[p][r*4+2], p3 = M[p][r*4+3];
        M[i][r*4+0] = p0*R[0] + p1*R[3] + p2*R[6];
        M[i][r*4+1] = p0*R[1] + p1*R[4] + p2*R[7];
        M[i][r*4+2] = p0*R[2] + p1*R[5] + p2*R[8];
        M[i][r*4+3] = p0*t0 + p1*t1 + p2*t2 + p3;
      }
    }
    #pragma unroll
    for (int r = 0; r < 3; ++r) {
      Gb[i*12 + r*4 + 0] = M[i][r*4+0];
      Gb[i*12 + r*4 + 1] = M[i][r*4+1];
      Gb[i*12 + r*4 + 2] = M[i][r*4+2];
      Gb[i*12 + r*4 + 3] = M[i][r*4+3]
          - (M[i][r*4+0]*J[i][0] + M[i][r*4+1]*J[i][1] + M[i][r*4+2]*J[i][2]);
    }
  }
}

// ---- fused pose-GEMM + LBS: block = 64 vertices x 64 batches ----
// thread (tx,ty): vertices v0+tx*4..+3, batches b0+ty*4..+3
__global__ __launch_bounds__(256) void k_skin2(
    const float* __restrict__ betas, const float* __restrict__ trans,
    const float* __restrict__ vtpl, const float* __restrict__ sd,
    const float* __restrict__ wgt,
    const float* __restrict__ pdirT, const float* __restrict__ wsLT,
    const float* __restrict__ wsG, float* __restrict__ out) {
  __shared__ float sm[10752];
  float* sA    = sm;            // 4672: sP(23x192) | sG(16x292) | sOut(16x192)
  float* sLt   = sm + 4672;     // 1472: sL(23x64)
  float* sW    = sm + 6144;     // 1600: 64x25 (padded)
  float* sBeta = sm + 7744;     // 640
  float* sTr   = sm + 8384;     // 192
  float* sVT   = sm + 8576;     // 192
  float* sSD   = sm + 8768;     // 1984: 64x31 (padded)

  const int tid = threadIdx.x;
  const int tx = tid & 15;
  const int ty = tid >> 4;
  const int v0 = blockIdx.x * 64;
  const int b0 = blockIdx.y * 64;
  const int vc0 = v0 * 3;

  // one-time staging
  for (int i = tid; i < 640; i += 256) sBeta[i] = betas[b0 * 10 + i];
  if (tid < 192) {
    sTr[tid] = trans[b0 * 3 + tid];
    sVT[tid] = (vc0 + tid < NVERT * 3) ? vtpl[vc0 + tid] : 0.f;
  }
  for (int i = tid; i < 1920; i += 256) {
    const int vl = i / 30, r = i - vl * 30;
    sSD[vl * 31 + r] = (v0 + vl < NVERT) ? sd[(size_t)(v0 + vl) * 30 + r] : 0.f;
  }
  for (int i = tid; i < 1536; i += 256) {
    const int vl = i / 24, j = i - vl * 24;
    sW[vl * 25 + j] = (v0 + vl < NVERT) ? wgt[(size_t)(v0 + vl) * 24 + j] : 0.f;
  }
  __syncthreads();

  // accumulator init = shape blend (v_template + shapedirs . beta)
  float acc[4][3][4];
  #pragma unroll
  for (int vi = 0; vi < 4; ++vi) {
    const int vl = tx * 4 + vi;
    float sdv[30];
    #pragma unroll
    for (int r = 0; r < 30; ++r) sdv[r] = sSD[vl * 31 + r];
    const float vt0 = sVT[vl*3+0], vt1 = sVT[vl*3+1], vt2 = sVT[vl*3+2];
    #pragma unroll
    for (int bi = 0; bi < 4; ++bi) {
      const int bl = ty * 4 + bi;
      float a0 = vt0, a1 = vt1, a2 = vt2;
      #pragma unroll
      for (int s = 0; s < 10; ++s) {
        const float be = sBeta[bl * 10 + s];
        a0 += be * sdv[s]; a1 += be * sdv[10 + s]; a2 += be * sdv[20 + s];
      }
      acc[vi][0][bi] = a0; acc[vi][1][bi] = a1; acc[vi][2][bi] = a2;
    }
  }

  // pose-blend GEMM: K=207 in 9 tiles of 23
  for (int kt = 0; kt < 9; ++kt) {
    __syncthreads();
    for (int i4 = tid; i4 < 1104; i4 += 256) {       // sP: 23x192
      const int k = i4 / 48, c4 = i4 - k * 48;
      *(float4*)&sA[k * 192 + c4 * 4] =
          *(const float4*)&pdirT[(size_t)(kt * 23 + k) * SPITCH + vc0 + c4 * 4];
    }
    for (int i4 = tid; i4 < 368; i4 += 256) {        // sL: 23x64
      const int k = i4 >> 4, c4 = i4 & 15;
      *(float4*)&sLt[k * 64 + c4 * 4] =
          *(const float4*)&wsLT[(size_t)(kt * 23 + k) * NBATCH + b0 + c4 * 4];
    }
    __syncthreads();
    #pragma unroll
    for (int k = 0; k < 23; ++k) {
      const float4 p0 = *(const float4*)&sA[k * 192 + tx * 12 + 0];
      const float4 p1 = *(const float4*)&sA[k * 192 + tx * 12 + 4];
      const float4 p2 = *(const float4*)&sA[k * 192 + tx * 12 + 8];
      const float4 l  = *(const float4*)&sLt[k * 64 + ty * 4];
      const float pv[12] = {p0.x,p0.y,p0.z,p0.w, p1.x,p1.y,p1.z,p1.w,
                            p2.x,p2.y,p2.z,p2.w};
      const float lv[4] = {l.x, l.y, l.z, l.w};
      #pragma unroll
      for (int vi = 0; vi < 4; ++vi)
        #pragma unroll
        for (int c = 0; c < 3; ++c)
          #pragma unroll
          for (int bi = 0; bi < 4; ++bi)
            acc[vi][c][bi] += pv[vi * 3 + c] * lv[bi];
    }
  }

  // epilogue: LBS in 4 batch phases (batches b0+4*ty+bi)
  const int vmax3 = min(192, (NVERT - v0) * 3);
  for (int bi = 0; bi < 4; ++bi) {
    __syncthreads();
    for (int i4 = tid; i4 < 1152; i4 += 256) {       // sG: 16 batches x 288 (stride 292)
      const int t = i4 / 72, e4 = i4 - t * 72;
      *(float4*)&sA[t * 292 + e4 * 4] =
          *(const float4*)&wsG[(size_t)(b0 + 4 * t + bi) * 288 + e4 * 4];
    }
    __syncthreads();
    float T[4][12];
    #pragma unroll
    for (int vi = 0; vi < 4; ++vi)
      #pragma unroll
      for (int k = 0; k < 12; ++k) T[vi][k] = 0.f;
    #pragma unroll
    for (int j = 0; j < 24; ++j) {
      const float4 g0 = *(const float4*)&sA[ty * 292 + j * 12 + 0];
      const float4 g1 = *(const float4*)&sA[ty * 292 + j * 12 + 4];
      const float4 g2 = *(const float4*)&sA[ty * 292 + j * 12 + 8];
      const float gv[12] = {g0.x,g0.y,g0.z,g0.w, g1.x,g1.y,g1.z,g1.w,
                            g2.x,g2.y,g2.z,g2.w};
      #pragma unroll
      for (int vi = 0; vi < 4; ++vi) {
        const float wj = sW[(tx * 4 + vi) * 25 + j];
        #pragma unroll
        for (int k = 0; k < 12; ++k) T[vi][k] += wj * gv[k];
      }
    }
    __syncthreads();
    const float tr0 = sTr[(4 * ty + bi) * 3 + 0];
    const float tr1 = sTr[(4 * ty + bi) * 3 + 1];
    const float tr2 = sTr[(4 * ty + bi) * 3 + 2];
    #pragma unroll
    for (int vi = 0; vi < 4; ++vi) {
      const float x = acc[vi][0][bi], y = acc[vi][1][bi], z = acc[vi][2][bi];
      const int o = ty * 192 + (tx * 4 + vi) * 3;
      sA[o + 0] = T[vi][0]*x + T[vi][1]*y + T[vi][2]*z  + T[vi][3]  + tr0;
      sA[o + 1] = T[vi][4]*x + T[vi][5]*y + T[vi][6]*z  + T[vi][7]  + tr1;
      sA[o + 2] = T[vi][8]*x + T[vi][9]*y + T[vi][10]*z + T[vi][11] + tr2;
    }
    __syncthreads();
    for (int f = tid; f < 3072; f += 256) {
      const int bl = f / 192, col = f - bl * 192;
      if (col < vmax3)
        out[(size_t)(b0 + 4 * bl + bi) * (NVERT * 3) + vc0 + col] = sA[f];
    }
  }
}

// ---- joints = Jr @ result ----
__global__ __launch_bounds__(256) void k_joints(
    const float* __restrict__ Jr, const float* __restrict__ res,
    float* __restrict__ joints) {
  const int b = blockIdx.x;
  const int lane = threadIdx.x & 63, wv = threadIdx.x >> 6;
  float acc[18];
  #pragma unroll
  for (int k = 0; k < 18; ++k) acc[k] = 0.f;
  const float* rb = res + (size_t)b * NVERT * 3;
  for (int v = lane; v < NVERT; v += 64) {
    const float r0 = rb[v*3+0], r1 = rb[v*3+1], r2 = rb[v*3+2];
    #pragma unroll
    for (int k = 0; k < 6; ++k) {
      const int j = wv + 4 * k;
      const float w = Jr[j * NVERT + v];
      acc[k*3+0] += w * r0; acc[k*3+1] += w * r1; acc[k*3+2] += w * r2;
    }
  }
  #pragma unroll
  for (int off = 32; off > 0; off >>= 1) {
    #pragma unroll
    for (int k = 0; k < 18; ++k) acc[k] += __shfl_down(acc[k], off, 64);
  }
  if (lane == 0) {
    #pragma unroll
    for (int k = 0; k < 6; ++k) {
      const int j = wv + 4 * k;
      joints[(size_t)b * 72 + j * 3 + 0] = acc[k*3+0];
      joints[(size_t)b * 72 + j * 3 + 1] = acc[k*3+1];
      joints[(size_t)b * 72 + j * 3 + 2] = acc[k*3+2];
    }
  }
}

extern "C" void kernel_launch(void* const* d_in, const int* in_sizes, int n_in,
                              void* d_out, int out_size, void* d_ws, size_t ws_size,
                              hipStream_t stream) {
  const float* betas  = (const float*)d_in[0];
  const float* thetas = (const float*)d_in[1];
  const float* trans  = (const float*)d_in[2];
  const float* scale  = (const float*)d_in[3];
  const float* vtpl   = (const float*)d_in[4];
  const float* sd     = (const float*)d_in[5];
  const float* pdir   = (const float*)d_in[6];
  const float* Jr     = (const float*)d_in[7];
  const float* wgt    = (const float*)d_in[8];
  float* out = (float*)d_out;

  float* ws    = (float*)d_ws;
  float* wsJ   = ws;                                   // 792
  float* wsG   = ws + 792;                             // 512*288
  float* wsLT  = wsG + (size_t)NBATCH * 288;           // 207*512
  float* pdirT = wsLT + (size_t)NPOSE * NBATCH;        // 207*20672
  float* wsJP  = pdirT + (size_t)NPOSE * SPITCH;       // 8*72*11

  k_tpose<<<dim3(SPITCH / 32, 7), dim3(32, 8), 0, stream>>>(pdir, pdirT);
  k_jreg1<<<dim3(72, 8), 256, 0, stream>>>(Jr, vtpl, sd, wsJP);
  k_jreg2<<<1, 128, 0, stream>>>(wsJP, wsJ);
  k_chain<<<NBATCH / 64, 64, 0, stream>>>(betas, thetas, scale, wsJ, wsG, wsLT);
  k_skin2<<<dim3(108, 8), 256, 0, stream>>>(betas, trans, vtpl, sd, wgt,
                                            pdirT, wsLT, wsG, out);
  k_joints<<<NBATCH, 256, 0, stream>>>(Jr, out, out + (size_t)NBATCH * NVERT * 3);
}

// Round 3
// 319.053 us; speedup vs baseline: 3.2113x; 1.6260x over previous
//
#include <hip/hip_runtime.h>

#define NVERT 6890
#define NJNT  24
#define NBETA 10
#define NPOSE 207
#define NBATCH 512
#define KPAD 224          // 207 pose + 10 shape + 1 template + 6 zero
#define MROWS 20736       // 108 * 192 >= 20670, zero-padded
#define NVC (NVERT * 3)   // 20670

typedef __attribute__((ext_vector_type(8))) short short8;
typedef __attribute__((ext_vector_type(4))) float floatx4;

__constant__ int c_par[NJNT] = {-1,0,0,0,1,2,3,4,5,6,7,8,9,9,9,12,13,14,16,17,18,19,20,21};

static __device__ __forceinline__ unsigned short f2bf(float x) {
  union { float f; unsigned u; } v; v.f = x;
  unsigned r = (v.u + 0x7FFFu + ((v.u >> 16) & 1u)) >> 16;
  return (unsigned short)r;
}

// ---- build augmented A (bf16, m-major [MROWS][224]) ----
// k<207: posedirs, 207..216: shapedirs, 217: v_template, else 0. rows>=20670 zero.
__global__ __launch_bounds__(256) void k_buildA(
    const float* __restrict__ pdir, const float* __restrict__ sd,
    const float* __restrict__ vt, unsigned short* __restrict__ AT) {
  const int idx = blockIdx.x * 256 + threadIdx.x;
  const int row = idx / KPAD, k = idx - row * KPAD;
  float val = 0.f;
  if (row < NVC) {
    if (k < NPOSE)            val = pdir[(size_t)row * NPOSE + k];
    else if (k < NPOSE + 10)  val = sd[(size_t)row * 10 + (k - NPOSE)];
    else if (k == NPOSE + 10) val = vt[row];
  }
  AT[idx] = f2bf(val);
}

// ---- Jreg stage 1: partial sums over 8 vertex chunks ----
__global__ __launch_bounds__(256) void k_jreg1(
    const float* __restrict__ Jr, const float* __restrict__ vt,
    const float* __restrict__ sd, float* __restrict__ wsJP) {
  const int jc = blockIdx.x, j = jc / 3, c = jc % 3;
  const int v0 = blockIdx.y * 864;
  const int vend = min(NVERT, v0 + 864);
  const int tid = threadIdx.x;
  float acc[11];
  #pragma unroll
  for (int k = 0; k < 11; ++k) acc[k] = 0.f;
  for (int v = v0 + tid; v < vend; v += 256) {
    const float w = Jr[j * NVERT + v];
    acc[0] += w * vt[v * 3 + c];
    const float* s = sd + (size_t)v * 30 + c * 10;
    #pragma unroll
    for (int k = 0; k < 10; ++k) acc[1 + k] += w * s[k];
  }
  #pragma unroll
  for (int off = 32; off > 0; off >>= 1) {
    #pragma unroll
    for (int k = 0; k < 11; ++k) acc[k] += __shfl_down(acc[k], off, 64);
  }
  __shared__ float red[4][11];
  const int lane = tid & 63, wv = tid >> 6;
  if (lane == 0) {
    #pragma unroll
    for (int k = 0; k < 11; ++k) red[wv][k] = acc[k];
  }
  __syncthreads();
  if (tid == 0) {
    #pragma unroll
    for (int k = 0; k < 11; ++k)
      wsJP[(size_t)(blockIdx.y * 72 + jc) * 11 + k] =
          red[0][k] + red[1][k] + red[2][k] + red[3][k];
  }
}

__global__ __launch_bounds__(128) void k_jreg2(const float* __restrict__ wsJP,
                                               float* __restrict__ wsJ) {
  const int jc = threadIdx.x;
  if (jc >= 72) return;
  #pragma unroll
  for (int k = 0; k < 11; ++k) {
    float s = 0.f;
    #pragma unroll
    for (int c8 = 0; c8 < 8; ++c8) s += wsJP[(size_t)(c8 * 72 + jc) * 11 + k];
    if (k == 0) wsJ[jc] = s;
    else        wsJ[72 + jc * 10 + (k - 1)] = s;
  }
}

// ---- chain: one thread/batch -> G [b][288] fp32, B-matrix row [b][224] bf16 ----
__global__ __launch_bounds__(64) void k_chain(
    const float* __restrict__ betas, const float* __restrict__ thetas,
    const float* __restrict__ scale, const float* __restrict__ wsJ,
    float* __restrict__ wsG, unsigned short* __restrict__ BT) {
  const int b = blockIdx.x * 64 + threadIdx.x;
  float be[NBETA];
  #pragma unroll
  for (int s = 0; s < NBETA; ++s) be[s] = betas[b * NBETA + s];
  float J[NJNT][3];
  for (int j = 0; j < NJNT; ++j) {
    #pragma unroll
    for (int c = 0; c < 3; ++c) {
      float a = wsJ[j * 3 + c];
      const float* d = wsJ + 72 + (j * 3 + c) * 10;
      #pragma unroll
      for (int s = 0; s < NBETA; ++s) a += d[s] * be[s];
      J[j][c] = a;
    }
  }
  const float sc = scale[0];
  float M[NJNT][12];
  float* Gb = wsG + (size_t)b * 288;
  unsigned short* Bb = BT + (size_t)b * KPAD;
  for (int i = 0; i < NJNT; ++i) {
    const float rx = thetas[b * 72 + i * 3 + 0];
    const float ry = thetas[b * 72 + i * 3 + 1];
    const float rz = thetas[b * 72 + i * 3 + 2];
    const float th = sqrtf(rx * rx + ry * ry + rz * rz) + 1e-8f;
    const float inv = 1.f / th;
    const float x = rx * inv, y = ry * inv, z = rz * inv;
    const float cs = cosf(th), sn = sinf(th), omc = 1.f - cs;
    float R[9];
    R[0] = cs + omc * x * x;     R[1] = omc * x * y - sn * z; R[2] = omc * x * z + sn * y;
    R[3] = omc * x * y + sn * z; R[4] = cs + omc * y * y;     R[5] = omc * y * z - sn * x;
    R[6] = omc * x * z - sn * y; R[7] = omc * y * z + sn * x; R[8] = cs + omc * z * z;
    if (i == 0) {
      #pragma unroll
      for (int k = 0; k < 9; ++k) R[k] *= sc;
    } else {
      #pragma unroll
      for (int k = 0; k < 9; ++k)
        Bb[(i - 1) * 9 + k] = f2bf(R[k] - ((k == 0 || k == 4 || k == 8) ? 1.f : 0.f));
    }
    if (i == 0) {
      #pragma unroll
      for (int r = 0; r < 3; ++r) {
        M[0][r*4+0] = R[r*3+0]; M[0][r*4+1] = R[r*3+1];
        M[0][r*4+2] = R[r*3+2]; M[0][r*4+3] = J[0][r];
      }
    } else {
      const int p = c_par[i];
      const float t0 = J[i][0] - J[p][0];
      const float t1 = J[i][1] - J[p][1];
      const float t2 = J[i][2] - J[p][2];
      for (int r = 0; r < 3; ++r) {
        const float p0 = M[p][r*4+0], p1 = M[p][r*4+1], p2 = M[p][r*4+2], p3 = M[p][r*4+3];
        M[i][r*4+0] = p0*R[0] + p1*R[3] + p2*R[6];
        M[i][r*4+1] = p0*R[1] + p1*R[4] + p2*R[7];
        M[i][r*4+2] = p0*R[2] + p1*R[5] + p2*R[8];
        M[i][r*4+3] = p0*t0 + p1*t1 + p2*t2 + p3;
      }
    }
    #pragma unroll
    for (int r = 0; r < 3; ++r) {
      Gb[i*12 + r*4 + 0] = M[i][r*4+0];
      Gb[i*12 + r*4 + 1] = M[i][r*4+1];
      Gb[i*12 + r*4 + 2] = M[i][r*4+2];
      Gb[i*12 + r*4 + 3] = M[i][r*4+3]
          - (M[i][r*4+0]*J[i][0] + M[i][r*4+1]*J[i][1] + M[i][r*4+2]*J[i][2]);
    }
  }
  // betas + constant-1 rows of the augmented B matrix
  #pragma unroll
  for (int s = 0; s < NBETA; ++s) Bb[NPOSE + s] = f2bf(be[s]);
  Bb[NPOSE + 10] = 0x3F80;   // bf16 1.0
  #pragma unroll
  for (int k = NPOSE + 11; k < KPAD; ++k) Bb[k] = 0;
}

// ---- fused MFMA pose+shape GEMM + VALU LBS. block: 192 vc-rows x 64 batches ----
__global__ __launch_bounds__(256, 3) void k_skin3(
    const unsigned short* __restrict__ AT, const unsigned short* __restrict__ BT,
    const float* __restrict__ wgt, const float* __restrict__ wsG,
    const float* __restrict__ trans, float* __restrict__ out) {
  // LDS pool (39680 B):
  //  GEMM phase:  sA bf16 [192][40] @short 0 (15360 B) | sB bf16 [64][40] @short 7680
  //  epilogue:    sW f32 [64][25] @f 0 | sV f32 [192][19] @f 1600 | sG f32 [16][292] @f 5248
  __shared__ float smem[9920];
  unsigned short* sAs = (unsigned short*)smem;
  unsigned short* sBs = (unsigned short*)smem + 7680;
  float* sW = smem;
  float* sV = smem + 1600;
  float* sG = smem + 5248;

  const int tid = threadIdx.x;
  const int wv = tid >> 6, lane = tid & 63;
  const int q = lane >> 4, n = lane & 15;
  const int vc0 = blockIdx.x * 192;
  const int v0 = blockIdx.x * 64;
  const int b0 = blockIdx.y * 64;

  floatx4 acc[3][4];
  #pragma unroll
  for (int mt = 0; mt < 3; ++mt)
    #pragma unroll
    for (int nt = 0; nt < 4; ++nt) acc[mt][nt] = (floatx4)(0.f);

  const int srow = tid >> 2, sj = tid & 3;   // staging: 4 threads/row
  for (int kt = 0; kt < 7; ++kt) {
    // stage A 192x32, B 64x32 (row stride 40 shorts = 80 B -> 2-way only)
    #pragma unroll
    for (int it = 0; it < 3; ++it) {
      const int row = it * 64 + srow;
      *(uint4*)(sAs + row * 40 + sj * 8) =
          *(const uint4*)(AT + (size_t)(vc0 + row) * KPAD + kt * 32 + sj * 8);
    }
    *(uint4*)(sBs + srow * 40 + sj * 8) =
        *(const uint4*)(BT + (size_t)(b0 + srow) * KPAD + kt * 32 + sj * 8);
    __syncthreads();
    short8 af[3], bf[4];
    #pragma unroll
    for (int mt = 0; mt < 3; ++mt)
      af[mt] = *(const short8*)(sAs + (48 * wv + 16 * mt + n) * 40 + q * 8);
    #pragma unroll
    for (int nt = 0; nt < 4; ++nt)
      bf[nt] = *(const short8*)(sBs + (16 * nt + n) * 40 + q * 8);
    #pragma unroll
    for (int mt = 0; mt < 3; ++mt)
      #pragma unroll
      for (int nt = 0; nt < 4; ++nt)
        acc[mt][nt] = __builtin_amdgcn_mfma_f32_16x16x32_bf16(
            af[mt], bf[nt], acc[mt][nt], 0, 0, 0);
    __syncthreads();
  }

  // stage skinning weights (overlaps old sA region; GEMM reads are done)
  for (int i = tid; i < 64 * 24; i += 256) {
    const int vl = i / 24, j = i - vl * 24;
    sW[vl * 25 + j] = (v0 + vl < NVERT) ? wgt[(size_t)(v0 + vl) * 24 + j] : 0.f;
  }

  const int vloc = lane;                    // vertex within block
  const bool vok = (v0 + vloc) < NVERT;
  float w[24];

  for (int nt = 0; nt < 4; ++nt) {
    __syncthreads();
    // acc -> sV (rows = vc_local, cols = batch in tile)
    #pragma unroll
    for (int mt = 0; mt < 3; ++mt)
      #pragma unroll
      for (int r = 0; r < 4; ++r)
        sV[(48 * wv + 16 * mt + 4 * q + r) * 19 + n] = acc[mt][nt][r];
    // stage G for this phase's 16 batches
    for (int i4 = tid; i4 < 1152; i4 += 256) {
      const int t = i4 / 72, e4 = i4 - t * 72;
      *(floatx4*)(sG + t * 292 + e4 * 4) =
          *(const floatx4*)(wsG + (size_t)(b0 + nt * 16 + t) * 288 + e4 * 4);
    }
    __syncthreads();
    if (nt == 0) {
      #pragma unroll
      for (int j = 0; j < 24; ++j) w[j] = sW[vloc * 25 + j];
    }
    #pragma unroll
    for (int kk = 0; kk < 4; ++kk) {
      const int bl = wv + 4 * kk;           // wave-uniform batch -> G broadcast
      const float* g = sG + bl * 292;
      float T[12];
      #pragma unroll
      for (int e = 0; e < 12; ++e) T[e] = 0.f;
      #pragma unroll
      for (int j = 0; j < 24; ++j) {
        const float wj = w[j];
        #pragma unroll
        for (int e = 0; e < 12; ++e) T[e] += wj * g[j * 12 + e];
      }
      const float x = sV[(3 * vloc + 0) * 19 + bl];
      const float y = sV[(3 * vloc + 1) * 19 + bl];
      const float z = sV[(3 * vloc + 2) * 19 + bl];
      const int bg = b0 + nt * 16 + bl;
      const float* tr = trans + (size_t)bg * 3;
      if (vok) {
        float* o = out + (size_t)bg * NVC + vc0 + 3 * vloc;
        o[0] = T[0]*x + T[1]*y + T[2]*z  + T[3]  + tr[0];
        o[1] = T[4]*x + T[5]*y + T[6]*z  + T[7]  + tr[1];
        o[2] = T[8]*x + T[9]*y + T[10]*z + T[11] + tr[2];
      }
    }
  }
}

// ---- joints = Jr @ result ----
__global__ __launch_bounds__(256) void k_joints(
    const float* __restrict__ Jr, const float* __restrict__ res,
    float* __restrict__ joints) {
  const int b = blockIdx.x;
  const int lane = threadIdx.x & 63, wv = threadIdx.x >> 6;
  float acc[18];
  #pragma unroll
  for (int k = 0; k < 18; ++k) acc[k] = 0.f;
  const float* rb = res + (size_t)b * NVC;
  for (int v = lane; v < NVERT; v += 64) {
    const float r0 = rb[v*3+0], r1 = rb[v*3+1], r2 = rb[v*3+2];
    #pragma unroll
    for (int k = 0; k < 6; ++k) {
      const int j = wv + 4 * k;
      const float w = Jr[j * NVERT + v];
      acc[k*3+0] += w * r0; acc[k*3+1] += w * r1; acc[k*3+2] += w * r2;
    }
  }
  #pragma unroll
  for (int off = 32; off > 0; off >>= 1) {
    #pragma unroll
    for (int k = 0; k < 18; ++k) acc[k] += __shfl_down(acc[k], off, 64);
  }
  if (lane == 0) {
    #pragma unroll
    for (int k = 0; k < 6; ++k) {
      const int j = wv + 4 * k;
      joints[(size_t)b * 72 + j * 3 + 0] = acc[k*3+0];
      joints[(size_t)b * 72 + j * 3 + 1] = acc[k*3+1];
      joints[(size_t)b * 72 + j * 3 + 2] = acc[k*3+2];
    }
  }
}

extern "C" void kernel_launch(void* const* d_in, const int* in_sizes, int n_in,
                              void* d_out, int out_size, void* d_ws, size_t ws_size,
                              hipStream_t stream) {
  const float* betas  = (const float*)d_in[0];
  const float* thetas = (const float*)d_in[1];
  const float* trans  = (const float*)d_in[2];
  const float* scale  = (const float*)d_in[3];
  const float* vtpl   = (const float*)d_in[4];
  const float* sd     = (const float*)d_in[5];
  const float* pdir   = (const float*)d_in[6];
  const float* Jr     = (const float*)d_in[7];
  const float* wgt    = (const float*)d_in[8];
  float* out = (float*)d_out;

  float* ws   = (float*)d_ws;
  float* wsJ  = ws;                                 // 792 floats
  float* wsJP = ws + 792;                           // 6336 floats
  float* wsG  = ws + 7128;                          // 512*288 = 147456 floats
  unsigned short* AT = (unsigned short*)(ws + 154584);     // MROWS*224 bf16
  unsigned short* BT = AT + (size_t)MROWS * KPAD;          // 512*224 bf16

  k_buildA<<<(MROWS * KPAD) / 256, 256, 0, stream>>>(pdir, sd, vtpl, AT);
  k_jreg1<<<dim3(72, 8), 256, 0, stream>>>(Jr, vtpl, sd, wsJP);
  k_jreg2<<<1, 128, 0, stream>>>(wsJP, wsJ);
  k_chain<<<NBATCH / 64, 64, 0, stream>>>(betas, thetas, scale, wsJ, wsG, BT);
  k_skin3<<<dim3(108, 8), 256, 0, stream>>>(AT, BT, wgt, wsG, trans, out);
  k_joints<<<NBATCH, 256, 0, stream>>>(Jr, out, out + (size_t)NBATCH * NVC);
}

// Round 4
// 257.505 us; speedup vs baseline: 3.9789x; 1.2390x over previous
//
#include <hip/hip_runtime.h>

#define NVERT 6890
#define NJNT  24
#define NBETA 10
#define NPOSE 207
#define NBATCH 512
#define KPAD 224          // 207 pose + 10 shape + 1 template + 6 zero
#define MROWS 20736       // 108 * 192 >= 20670
#define NVC (NVERT * 3)   // 20670

typedef __attribute__((ext_vector_type(8))) short short8;
typedef __attribute__((ext_vector_type(4))) float floatx4;

__constant__ int c_par[NJNT] = {-1,0,0,0,1,2,3,4,5,6,7,8,9,9,9,12,13,14,16,17,18,19,20,21};

static __device__ __forceinline__ unsigned short f2bf(float x) {
  union { float f; unsigned u; } v; v.f = x;
  unsigned r = (v.u + 0x7FFFu + ((v.u >> 16) & 1u)) >> 16;
  return (unsigned short)r;
}
static __device__ __forceinline__ float bf2f(unsigned short h) {
  union { unsigned u; float f; } v; v.u = (unsigned)h << 16;
  return v.f;
}

// ---- build augmented A (bf16, m-major [MROWS][224]) ----
__global__ __launch_bounds__(256) void k_buildA(
    const float* __restrict__ pdir, const float* __restrict__ sd,
    const float* __restrict__ vt, unsigned short* __restrict__ AT) {
  const int idx = blockIdx.x * 256 + threadIdx.x;
  const int row = idx / KPAD, k = idx - row * KPAD;
  float val = 0.f;
  if (row < NVC) {
    if (k < NPOSE)            val = pdir[(size_t)row * NPOSE + k];
    else if (k < NPOSE + 10)  val = sd[(size_t)row * 10 + (k - NPOSE)];
    else if (k == NPOSE + 10) val = vt[row];
  }
  AT[idx] = f2bf(val);
}

// ---- build W hi/lo bf16: W16[v][64] = [hi j0..31 | lo j0..31], j>=24 or v>=NVERT -> 0
__global__ __launch_bounds__(256) void k_buildW(
    const float* __restrict__ wgt, unsigned short* __restrict__ W16) {
  const int idx = blockIdx.x * 256 + threadIdx.x;   // < 6912*64
  const int v = idx >> 6, c = idx & 63, j = c & 31, h = c >> 5;
  const float w = (v < NVERT && j < 24) ? wgt[(size_t)v * 24 + j] : 0.f;
  const unsigned short hi = f2bf(w);
  W16[idx] = h ? f2bf(w - bf2f(hi)) : hi;
}

// ---- Jreg stage 1: partial sums over 8 vertex chunks ----
__global__ __launch_bounds__(256) void k_jreg1(
    const float* __restrict__ Jr, const float* __restrict__ vt,
    const float* __restrict__ sd, float* __restrict__ wsJP) {
  const int jc = blockIdx.x, j = jc / 3, c = jc % 3;
  const int v0 = blockIdx.y * 864;
  const int vend = min(NVERT, v0 + 864);
  const int tid = threadIdx.x;
  float acc[11];
  #pragma unroll
  for (int k = 0; k < 11; ++k) acc[k] = 0.f;
  for (int v = v0 + tid; v < vend; v += 256) {
    const float w = Jr[j * NVERT + v];
    acc[0] += w * vt[v * 3 + c];
    const float* s = sd + (size_t)v * 30 + c * 10;
    #pragma unroll
    for (int k = 0; k < 10; ++k) acc[1 + k] += w * s[k];
  }
  #pragma unroll
  for (int off = 32; off > 0; off >>= 1) {
    #pragma unroll
    for (int k = 0; k < 11; ++k) acc[k] += __shfl_down(acc[k], off, 64);
  }
  __shared__ float red[4][11];
  const int lane = tid & 63, wv = tid >> 6;
  if (lane == 0) {
    #pragma unroll
    for (int k = 0; k < 11; ++k) red[wv][k] = acc[k];
  }
  __syncthreads();
  if (tid == 0) {
    #pragma unroll
    for (int k = 0; k < 11; ++k)
      wsJP[(size_t)(blockIdx.y * 72 + jc) * 11 + k] =
          red[0][k] + red[1][k] + red[2][k] + red[3][k];
  }
}

// ---- chain (merged jreg2): 4 blocks x 128 thr; thread = batch ----
__global__ __launch_bounds__(128, 1) void k_chain2(
    const float* __restrict__ betas, const float* __restrict__ thetas,
    const float* __restrict__ scale, const float* __restrict__ wsJP,
    float* __restrict__ wsG, unsigned short* __restrict__ BT) {
  __shared__ float sJ[792];
  const int tid = threadIdx.x;
  if (tid < 72) {
    #pragma unroll
    for (int k = 0; k < 11; ++k) {
      float s = 0.f;
      #pragma unroll
      for (int c8 = 0; c8 < 8; ++c8) s += wsJP[(size_t)(c8 * 72 + tid) * 11 + k];
      if (k == 0) sJ[tid] = s;
      else        sJ[72 + tid * 10 + (k - 1)] = s;
    }
  }
  __syncthreads();
  const int b = blockIdx.x * 128 + tid;
  float be[NBETA];
  #pragma unroll
  for (int s = 0; s < NBETA; ++s) be[s] = betas[b * NBETA + s];
  float J[NJNT][3];
  for (int j = 0; j < NJNT; ++j) {
    #pragma unroll
    for (int c = 0; c < 3; ++c) {
      float a = sJ[j * 3 + c];
      const float* d = sJ + 72 + (j * 3 + c) * 10;
      #pragma unroll
      for (int s = 0; s < NBETA; ++s) a += d[s] * be[s];
      J[j][c] = a;
    }
  }
  const float sc = scale[0];
  float M[NJNT][12];
  float* Gb = wsG + (size_t)b * 288;
  unsigned short* Bb = BT + (size_t)b * KPAD;
  for (int i = 0; i < NJNT; ++i) {
    const float rx = thetas[b * 72 + i * 3 + 0];
    const float ry = thetas[b * 72 + i * 3 + 1];
    const float rz = thetas[b * 72 + i * 3 + 2];
    const float th = sqrtf(rx * rx + ry * ry + rz * rz) + 1e-8f;
    const float inv = 1.f / th;
    const float x = rx * inv, y = ry * inv, z = rz * inv;
    const float cs = cosf(th), sn = sinf(th), omc = 1.f - cs;
    float R[9];
    R[0] = cs + omc * x * x;     R[1] = omc * x * y - sn * z; R[2] = omc * x * z + sn * y;
    R[3] = omc * x * y + sn * z; R[4] = cs + omc * y * y;     R[5] = omc * y * z - sn * x;
    R[6] = omc * x * z - sn * y; R[7] = omc * y * z + sn * x; R[8] = cs + omc * z * z;
    if (i == 0) {
      #pragma unroll
      for (int k = 0; k < 9; ++k) R[k] *= sc;
    } else {
      #pragma unroll
      for (int k = 0; k < 9; ++k)
        Bb[(i - 1) * 9 + k] = f2bf(R[k] - ((k == 0 || k == 4 || k == 8) ? 1.f : 0.f));
    }
    if (i == 0) {
      #pragma unroll
      for (int r = 0; r < 3; ++r) {
        M[0][r*4+0] = R[r*3+0]; M[0][r*4+1] = R[r*3+1];
        M[0][r*4+2] = R[r*3+2]; M[0][r*4+3] = J[0][r];
      }
    } else {
      const int p = c_par[i];
      const float t0 = J[i][0] - J[p][0];
      const float t1 = J[i][1] - J[p][1];
      const float t2 = J[i][2] - J[p][2];
      for (int r = 0; r < 3; ++r) {
        const float p0 = M[p][r*4+0], p1 = M[p][r*4+1], p2 = M[p][r*4+2], p3 = M[p][r*4+3];
        M[i][r*4+0] = p0*R[0] + p1*R[3] + p2*R[6];
        M[i][r*4+1] = p0*R[1] + p1*R[4] + p2*R[7];
        M[i][r*4+2] = p0*R[2] + p1*R[5] + p2*R[8];
        M[i][r*4+3] = p0*t0 + p1*t1 + p2*t2 + p3;
      }
    }
    #pragma unroll
    for (int r = 0; r < 3; ++r) {
      Gb[i*12 + r*4 + 0] = M[i][r*4+0];
      Gb[i*12 + r*4 + 1] = M[i][r*4+1];
      Gb[i*12 + r*4 + 2] = M[i][r*4+2];
      Gb[i*12 + r*4 + 3] = M[i][r*4+3]
          - (M[i][r*4+0]*J[i][0] + M[i][r*4+1]*J[i][1] + M[i][r*4+2]*J[i][2]);
    }
  }
  #pragma unroll
  for (int s = 0; s < NBETA; ++s) Bb[NPOSE + s] = f2bf(be[s]);
  Bb[NPOSE + 10] = 0x3F80;   // bf16 1.0
  #pragma unroll
  for (int k = NPOSE + 11; k < KPAD; ++k) Bb[k] = 0;
}

// ---- split G into bf16 hi/lo in MFMA-A layout [b][h][e=16][j=32], fold trans ----
// valid since skinning weights sum to 1: sum_j w (t_j + tr) = sum_j w t_j + tr
__global__ __launch_bounds__(256) void k_gsplit(
    const float* __restrict__ Gf, const float* __restrict__ trans,
    unsigned short* __restrict__ G16) {
  const int idx = blockIdx.x * 256 + threadIdx.x;   // < 512*512
  const int b = idx >> 9, rem = idx & 511, e = rem >> 5, j = rem & 31;
  float g = 0.f;
  if (e < 12 && j < 24) {
    g = Gf[(size_t)b * 288 + j * 12 + e];
    if ((e & 3) == 3) g += trans[b * 3 + (e >> 2)];
  }
  const unsigned short hi = f2bf(g);
  G16[(size_t)b * 1024 + e * 32 + j]       = hi;
  G16[(size_t)b * 1024 + 512 + e * 32 + j] = f2bf(g - bf2f(hi));
}

// ---- fused MFMA pose+shape GEMM + MFMA LBS. block: 192 vc x 64 batches ----
__global__ __launch_bounds__(256, 3) void k_skin4(
    const unsigned short* __restrict__ AT, const unsigned short* __restrict__ BT,
    const unsigned short* __restrict__ W16, const unsigned short* __restrict__ G16,
    float* __restrict__ out) {
  __shared__ __align__(16) char smem[43776];
  unsigned short* sAs = (unsigned short*)smem;             // [192][40] GEMM A
  unsigned short* sBs = (unsigned short*)(smem + 15360);   // [64][40]  GEMM B
  float* sV           = (float*)smem;                      // [192][17] epi: vph
  unsigned short* sG2 = (unsigned short*)(smem + 13056);   // [256][40] epi: G hi/lo
  unsigned short* sWh = (unsigned short*)(smem + 33536);   // [64][40]  W hi
  unsigned short* sWl = (unsigned short*)(smem + 38656);   // [64][40]  W lo

  const int tid = threadIdx.x;
  const int wv = tid >> 6, lane = tid & 63;
  const int q = lane >> 4, n = lane & 15;
  const int b0 = blockIdx.x * 64;       // x = batch tile (8) -> AT stays L2-hot
  const int vc0 = blockIdx.y * 192;

  // stage W hi/lo once (separate region, made visible by first barrier)
  for (int i = tid; i < 512; i += 256) {
    const int row = i >> 3, c8 = i & 7;
    const uint4 w = *(const uint4*)(W16 + (size_t)(blockIdx.y * 64 + row) * 64 + c8 * 8);
    if (c8 < 4) *(uint4*)(sWh + row * 40 + c8 * 8) = w;
    else        *(uint4*)(sWl + row * 40 + (c8 - 4) * 8) = w;
  }

  floatx4 acc[3][4];
  #pragma unroll
  for (int mt = 0; mt < 3; ++mt)
    #pragma unroll
    for (int nt = 0; nt < 4; ++nt) acc[mt][nt] = (floatx4)(0.f);

  const int srow = tid >> 2, sj = tid & 3;
  for (int kt = 0; kt < 7; ++kt) {
    if (kt) __syncthreads();
    #pragma unroll
    for (int it = 0; it < 3; ++it) {
      const int row = it * 64 + srow;
      *(uint4*)(sAs + row * 40 + sj * 8) =
          *(const uint4*)(AT + (size_t)(vc0 + row) * KPAD + kt * 32 + sj * 8);
    }
    *(uint4*)(sBs + srow * 40 + sj * 8) =
        *(const uint4*)(BT + (size_t)(b0 + srow) * KPAD + kt * 32 + sj * 8);
    __syncthreads();
    short8 af[3], bfr[4];
    #pragma unroll
    for (int mt = 0; mt < 3; ++mt)
      af[mt] = *(const short8*)(sAs + (48 * wv + 16 * mt + n) * 40 + q * 8);
    #pragma unroll
    for (int nt = 0; nt < 4; ++nt)
      bfr[nt] = *(const short8*)(sBs + (16 * nt + n) * 40 + q * 8);
    #pragma unroll
    for (int mt = 0; mt < 3; ++mt)
      #pragma unroll
      for (int nt = 0; nt < 4; ++nt)
        acc[mt][nt] = __builtin_amdgcn_mfma_f32_16x16x32_bf16(
            af[mt], bfr[nt], acc[mt][nt], 0, 0, 0);
  }

  // preload W fragments (B operand of LBS GEMM), fixed for whole block
  short8 wh[4], wl[4];
  #pragma unroll
  for (int vt = 0; vt < 4; ++vt) {
    wh[vt] = *(const short8*)(sWh + (vt * 16 + n) * 40 + q * 8);
    wl[vt] = *(const short8*)(sWl + (vt * 16 + n) * 40 + q * 8);
  }

  // epilogue: per 16-batch phase (nt), two 8-batch sub-rounds (s)
  for (int nt = 0; nt < 4; ++nt) {
    for (int s = 0; s < 2; ++s) {
      __syncthreads();
      if (s == 0) {
        #pragma unroll
        for (int mt = 0; mt < 3; ++mt)
          #pragma unroll
          for (int r = 0; r < 4; ++r)
            sV[(48 * wv + 16 * mt + 4 * q + r) * 17 + n] = acc[mt][nt][r];
      }
      const int bg0 = b0 + nt * 16 + s * 8;
      for (int i = tid; i < 1024; i += 256) {
        const int row = i >> 2, c4 = i & 3;
        const int t = row >> 5, rem = row & 31;
        *(uint4*)(sG2 + row * 40 + c4 * 8) =
            *(const uint4*)(G16 + (size_t)(bg0 + t) * 1024 + rem * 32 + c4 * 8);
      }
      __syncthreads();
      #pragma unroll
      for (int bb = 0; bb < 2; ++bb) {
        const int t = wv * 2 + bb;
        const int col = s * 8 + t;
        const int bg = b0 + nt * 16 + col;
        const short8 gh = *(const short8*)(sG2 + (t * 32 + n) * 40 + q * 8);
        const short8 gl = *(const short8*)(sG2 + (t * 32 + 16 + n) * 40 + q * 8);
        #pragma unroll
        for (int vt = 0; vt < 4; ++vt) {
          floatx4 a2 = (floatx4)(0.f);
          a2 = __builtin_amdgcn_mfma_f32_16x16x32_bf16(gh, wl[vt], a2, 0, 0, 0);
          a2 = __builtin_amdgcn_mfma_f32_16x16x32_bf16(gl, wh[vt], a2, 0, 0, 0);
          a2 = __builtin_amdgcn_mfma_f32_16x16x32_bf16(gh, wh[vt], a2, 0, 0, 0);
          const float X = sV[(48 * vt + 3 * n + 0) * 17 + col];
          const float Y = sV[(48 * vt + 3 * n + 1) * 17 + col];
          const float Z = sV[(48 * vt + 3 * n + 2) * 17 + col];
          const float o = a2[0] * X + a2[1] * Y + a2[2] * Z + a2[3];
          const int vc = vc0 + 48 * vt + 3 * n + q;
          if (q < 3 && vc < NVC)
            out[(size_t)bg * NVC + vc] = o;
        }
      }
    }
  }
}

// ---- joints = Jr @ result ----
__global__ __launch_bounds__(256) void k_joints(
    const float* __restrict__ Jr, const float* __restrict__ res,
    float* __restrict__ joints) {
  const int b = blockIdx.x;
  const int lane = threadIdx.x & 63, wv = threadIdx.x >> 6;
  float acc[18];
  #pragma unroll
  for (int k = 0; k < 18; ++k) acc[k] = 0.f;
  const float* rb = res + (size_t)b * NVC;
  for (int v = lane; v < NVERT; v += 64) {
    const float r0 = rb[v*3+0], r1 = rb[v*3+1], r2 = rb[v*3+2];
    #pragma unroll
    for (int k = 0; k < 6; ++k) {
      const int j = wv + 4 * k;
      const float w = Jr[j * NVERT + v];
      acc[k*3+0] += w * r0; acc[k*3+1] += w * r1; acc[k*3+2] += w * r2;
    }
  }
  #pragma unroll
  for (int off = 32; off > 0; off >>= 1) {
    #pragma unroll
    for (int k = 0; k < 18; ++k) acc[k] += __shfl_down(acc[k], off, 64);
  }
  if (lane == 0) {
    #pragma unroll
    for (int k = 0; k < 6; ++k) {
      const int j = wv + 4 * k;
      joints[(size_t)b * 72 + j * 3 + 0] = acc[k*3+0];
      joints[(size_t)b * 72 + j * 3 + 1] = acc[k*3+1];
      joints[(size_t)b * 72 + j * 3 + 2] = acc[k*3+2];
    }
  }
}

extern "C" void kernel_launch(void* const* d_in, const int* in_sizes, int n_in,
                              void* d_out, int out_size, void* d_ws, size_t ws_size,
                              hipStream_t stream) {
  const float* betas  = (const float*)d_in[0];
  const float* thetas = (const float*)d_in[1];
  const float* trans  = (const float*)d_in[2];
  const float* scale  = (const float*)d_in[3];
  const float* vtpl   = (const float*)d_in[4];
  const float* sd     = (const float*)d_in[5];
  const float* pdir   = (const float*)d_in[6];
  const float* Jr     = (const float*)d_in[7];
  const float* wgt    = (const float*)d_in[8];
  float* out = (float*)d_out;

  float* ws   = (float*)d_ws;
  float* wsJP = ws;                                  // 6336 floats
  float* wsG  = ws + 6336;                           // 512*288 floats
  unsigned short* AT  = (unsigned short*)(ws + 153792);      // MROWS*224
  unsigned short* BT  = AT + (size_t)MROWS * KPAD;           // 512*224
  unsigned short* W16 = BT + (size_t)NBATCH * KPAD;          // 6912*64
  unsigned short* G16 = W16 + (size_t)6912 * 64;             // 512*1024

  k_buildA<<<(MROWS * KPAD) / 256, 256, 0, stream>>>(pdir, sd, vtpl, AT);
  k_buildW<<<(6912 * 64) / 256, 256, 0, stream>>>(wgt, W16);
  k_jreg1<<<dim3(72, 8), 256, 0, stream>>>(Jr, vtpl, sd, wsJP);
  k_chain2<<<4, 128, 0, stream>>>(betas, thetas, scale, wsJP, wsG, BT);
  k_gsplit<<<(NBATCH * 512) / 256, 256, 0, stream>>>(wsG, trans, G16);
  k_skin4<<<dim3(8, 108), 256, 0, stream>>>(AT, BT, W16, G16, out);
  k_joints<<<NBATCH, 256, 0, stream>>>(Jr, out, out + (size_t)NBATCH * NVC);
}

// Round 5
// 204.852 us; speedup vs baseline: 5.0016x; 1.2570x over previous
//
#include <hip/hip_runtime.h>

#define NVERT 6890
#define NJNT  24
#define NBETA 10
#define NPOSE 207
#define NBATCH 512
#define KPAD 224          // 207 pose + 10 shape + 1 template + 6 zero
#define MROWS 20736       // 108 * 192 >= 20670
#define NVC (NVERT * 3)   // 20670

typedef __attribute__((ext_vector_type(8))) short short8;
typedef __attribute__((ext_vector_type(4))) float floatx4;

__constant__ int c_par[NJNT]   = {-1,0,0,0,1,2,3,4,5,6,7,8,9,9,9,12,13,14,16,17,18,19,20,21};
__constant__ int c_depth[NJNT] = { 0,1,1,1,2,2,2,3,3,3,4,4,4,4,4,5,5,5,6,6,7,7,8,8};

static __device__ __forceinline__ unsigned short f2bf(float x) {
  union { float f; unsigned u; } v; v.f = x;
  unsigned r = (v.u + 0x7FFFu + ((v.u >> 16) & 1u)) >> 16;
  return (unsigned short)r;
}
static __device__ __forceinline__ float bf2f(unsigned short h) {
  union { unsigned u; float f; } v; v.u = (unsigned)h << 16;
  return v.f;
}

// ---- build augmented A (bf16, m-major [MROWS][224]) ----
__global__ __launch_bounds__(256) void k_buildA(
    const float* __restrict__ pdir, const float* __restrict__ sd,
    const float* __restrict__ vt, unsigned short* __restrict__ AT) {
  const int idx = blockIdx.x * 256 + threadIdx.x;
  const int row = idx / KPAD, k = idx - row * KPAD;
  float val = 0.f;
  if (row < NVC) {
    if (k < NPOSE)            val = pdir[(size_t)row * NPOSE + k];
    else if (k < NPOSE + 10)  val = sd[(size_t)row * 10 + (k - NPOSE)];
    else if (k == NPOSE + 10) val = vt[row];
  }
  AT[idx] = f2bf(val);
}

// ---- build W hi/lo bf16: W16[v][64] = [hi j0..31 | lo j0..31] ----
__global__ __launch_bounds__(256) void k_buildW(
    const float* __restrict__ wgt, unsigned short* __restrict__ W16) {
  const int idx = blockIdx.x * 256 + threadIdx.x;   // < 6912*64
  const int v = idx >> 6, c = idx & 63, j = c & 31, h = c >> 5;
  const float w = (v < NVERT && j < 24) ? wgt[(size_t)v * 24 + j] : 0.f;
  const unsigned short hi = f2bf(w);
  W16[idx] = h ? f2bf(w - bf2f(hi)) : hi;
}

// ---- Jreg stage 1: partial sums over 8 vertex chunks ----
__global__ __launch_bounds__(256) void k_jreg1(
    const float* __restrict__ Jr, const float* __restrict__ vt,
    const float* __restrict__ sd, float* __restrict__ wsJP) {
  const int jc = blockIdx.x, j = jc / 3, c = jc % 3;
  const int v0 = blockIdx.y * 864;
  const int vend = min(NVERT, v0 + 864);
  const int tid = threadIdx.x;
  float acc[11];
  #pragma unroll
  for (int k = 0; k < 11; ++k) acc[k] = 0.f;
  for (int v = v0 + tid; v < vend; v += 256) {
    const float w = Jr[j * NVERT + v];
    acc[0] += w * vt[v * 3 + c];
    const float* s = sd + (size_t)v * 30 + c * 10;
    #pragma unroll
    for (int k = 0; k < 10; ++k) acc[1 + k] += w * s[k];
  }
  #pragma unroll
  for (int off = 32; off > 0; off >>= 1) {
    #pragma unroll
    for (int k = 0; k < 11; ++k) acc[k] += __shfl_down(acc[k], off, 64);
  }
  __shared__ float red[4][11];
  const int lane = tid & 63, wv = tid >> 6;
  if (lane == 0) {
    #pragma unroll
    for (int k = 0; k < 11; ++k) red[wv][k] = acc[k];
  }
  __syncthreads();
  if (tid == 0) {
    #pragma unroll
    for (int k = 0; k < 11; ++k)
      wsJP[(size_t)(blockIdx.y * 72 + jc) * 11 + k] =
          red[0][k] + red[1][k] + red[2][k] + red[3][k];
  }
}

// ---- chain v3: wave per batch, lane = joint, tree-level parallel ----
// Writes BT (bf16 GEMM-B rows) and G16 (hi/lo bf16 MFMA-A layout, trans folded).
__global__ __launch_bounds__(256, 2) void k_chain3(
    const float* __restrict__ betas, const float* __restrict__ thetas,
    const float* __restrict__ scale, const float* __restrict__ trans,
    const float* __restrict__ wsJP,
    unsigned short* __restrict__ BT, unsigned short* __restrict__ G16) {
  __shared__ __align__(16) float sJ[792];
  __shared__ __align__(16) float sJJ[4][72];
  __shared__ __align__(16) float sM[4][288];
  __shared__ __align__(16) unsigned short sG[4][1024];
  __shared__ __align__(16) unsigned short sB[4][KPAD];

  const int tid = threadIdx.x;
  const int wv = tid >> 6, lane = tid & 63;
  const int b = blockIdx.x * 4 + wv;

  if (tid < 72) {
    #pragma unroll
    for (int k = 0; k < 11; ++k) {
      float s = 0.f;
      #pragma unroll
      for (int c8 = 0; c8 < 8; ++c8) s += wsJP[(size_t)(c8 * 72 + tid) * 11 + k];
      if (k == 0) sJ[tid] = s;
      else        sJ[72 + tid * 10 + (k - 1)] = s;
    }
  }
  #pragma unroll
  for (int r = 0; r < 4; ++r) {
    sG[wv][lane * 16 + r * 4 + 0] = 0; sG[wv][lane * 16 + r * 4 + 1] = 0;
    sG[wv][lane * 16 + r * 4 + 2] = 0; sG[wv][lane * 16 + r * 4 + 3] = 0;
  }
  __syncthreads();

  float R[9], t[3], M[12], Jx = 0.f, Jy = 0.f, Jz = 0.f;
  const int i = lane;
  if (i < NJNT) {
    #pragma unroll
    for (int c = 0; c < 3; ++c) {
      float a = sJ[i * 3 + c];
      const float* d = sJ + 72 + (i * 3 + c) * 10;
      #pragma unroll
      for (int s = 0; s < NBETA; ++s) a += d[s] * betas[b * NBETA + s];
      if (c == 0) Jx = a; else if (c == 1) Jy = a; else Jz = a;
    }
    sJJ[wv][i * 3 + 0] = Jx; sJJ[wv][i * 3 + 1] = Jy; sJJ[wv][i * 3 + 2] = Jz;
    const float rx = thetas[b * 72 + i * 3 + 0];
    const float ry = thetas[b * 72 + i * 3 + 1];
    const float rz = thetas[b * 72 + i * 3 + 2];
    const float th = sqrtf(rx * rx + ry * ry + rz * rz) + 1e-8f;
    const float inv = 1.f / th;
    const float x = rx * inv, y = ry * inv, z = rz * inv;
    const float cs = cosf(th), sn = sinf(th), omc = 1.f - cs;
    R[0] = cs + omc * x * x;     R[1] = omc * x * y - sn * z; R[2] = omc * x * z + sn * y;
    R[3] = omc * x * y + sn * z; R[4] = cs + omc * y * y;     R[5] = omc * y * z - sn * x;
    R[6] = omc * x * z - sn * y; R[7] = omc * y * z + sn * x; R[8] = cs + omc * z * z;
    if (i == 0) {
      const float sc = scale[0];
      #pragma unroll
      for (int k = 0; k < 9; ++k) R[k] *= sc;
    } else {
      #pragma unroll
      for (int k = 0; k < 9; ++k)
        sB[wv][(i - 1) * 9 + k] = f2bf(R[k] - ((k == 0 || k == 4 || k == 8) ? 1.f : 0.f));
    }
  }
  if (i == 0) {
    #pragma unroll
    for (int s = 0; s < NBETA; ++s) sB[wv][NPOSE + s] = f2bf(betas[b * NBETA + s]);
    sB[wv][NPOSE + 10] = 0x3F80;
    #pragma unroll
    for (int k = NPOSE + 11; k < KPAD; ++k) sB[wv][k] = 0;
  }
  __syncthreads();

  if (i < NJNT) {
    if (i == 0) { t[0] = Jx; t[1] = Jy; t[2] = Jz; }
    else {
      const int p = c_par[i];
      t[0] = Jx - sJJ[wv][p * 3 + 0];
      t[1] = Jy - sJJ[wv][p * 3 + 1];
      t[2] = Jz - sJJ[wv][p * 3 + 2];
    }
    if (i == 0) {
      #pragma unroll
      for (int r = 0; r < 3; ++r) {
        M[r*4+0] = R[r*3+0]; M[r*4+1] = R[r*3+1]; M[r*4+2] = R[r*3+2]; M[r*4+3] = t[r];
      }
      #pragma unroll
      for (int k = 0; k < 12; ++k) sM[wv][k] = M[k];
    }
  }
  __syncthreads();

  for (int lvl = 1; lvl <= 8; ++lvl) {
    if (i < NJNT && c_depth[i] == lvl) {
      const float* Mp = sM[wv] + c_par[i] * 12;
      #pragma unroll
      for (int r = 0; r < 3; ++r) {
        const float p0 = Mp[r*4+0], p1 = Mp[r*4+1], p2 = Mp[r*4+2], p3 = Mp[r*4+3];
        M[r*4+0] = p0*R[0] + p1*R[3] + p2*R[6];
        M[r*4+1] = p0*R[1] + p1*R[4] + p2*R[7];
        M[r*4+2] = p0*R[2] + p1*R[5] + p2*R[8];
        M[r*4+3] = p0*t[0] + p1*t[1] + p2*t[2] + p3;
      }
      #pragma unroll
      for (int k = 0; k < 12; ++k) sM[wv][i * 12 + k] = M[k];
    }
    __syncthreads();
  }

  // G: t-col -= M@J_i, fold trans; hi/lo bf16 split into MFMA-A layout
  if (i < NJNT) {
    #pragma unroll
    for (int r = 0; r < 3; ++r) {
      M[r*4+3] = M[r*4+3] - (M[r*4+0]*Jx + M[r*4+1]*Jy + M[r*4+2]*Jz)
               + trans[b * 3 + r];
    }
    #pragma unroll
    for (int e = 0; e < 12; ++e) {
      const float g = M[e];
      const unsigned short hi = f2bf(g);
      sG[wv][e * 32 + i]       = hi;
      sG[wv][512 + e * 32 + i] = f2bf(g - bf2f(hi));
    }
  }
  __syncthreads();

  // coalesced global writes
  *(uint4*)(G16 + (size_t)b * 1024 + lane * 16)     = *(uint4*)&sG[wv][lane * 16];
  *(uint4*)(G16 + (size_t)b * 1024 + lane * 16 + 8) = *(uint4*)&sG[wv][lane * 16 + 8];
  if (lane < 28)
    *(uint4*)(BT + (size_t)b * KPAD + lane * 8) = *(uint4*)&sB[wv][lane * 8];
}

// ---- fused MFMA pose+shape GEMM + MFMA LBS. block: 192 vc x 64 batches ----
__global__ __launch_bounds__(256, 3) void k_skin4(
    const unsigned short* __restrict__ AT, const unsigned short* __restrict__ BT,
    const unsigned short* __restrict__ W16, const unsigned short* __restrict__ G16,
    float* __restrict__ out) {
  __shared__ __align__(16) char smem[43776];
  unsigned short* sAs = (unsigned short*)smem;             // [192][40] GEMM A
  unsigned short* sBs = (unsigned short*)(smem + 15360);   // [64][40]  GEMM B
  float* sV           = (float*)smem;                      // [192][17] epi: vph
  unsigned short* sG2 = (unsigned short*)(smem + 13056);   // [256][40] epi: G hi/lo
  unsigned short* sWh = (unsigned short*)(smem + 33536);   // [64][40]  W hi
  unsigned short* sWl = (unsigned short*)(smem + 38656);   // [64][40]  W lo

  const int tid = threadIdx.x;
  const int wv = tid >> 6, lane = tid & 63;
  const int q = lane >> 4, n = lane & 15;
  const int b0 = blockIdx.x * 64;
  const int vc0 = blockIdx.y * 192;

  for (int i = tid; i < 512; i += 256) {
    const int row = i >> 3, c8 = i & 7;
    const uint4 w = *(const uint4*)(W16 + (size_t)(blockIdx.y * 64 + row) * 64 + c8 * 8);
    if (c8 < 4) *(uint4*)(sWh + row * 40 + c8 * 8) = w;
    else        *(uint4*)(sWl + row * 40 + (c8 - 4) * 8) = w;
  }

  floatx4 acc[3][4];
  #pragma unroll
  for (int mt = 0; mt < 3; ++mt)
    #pragma unroll
    for (int nt = 0; nt < 4; ++nt) acc[mt][nt] = (floatx4)(0.f);

  const int srow = tid >> 2, sj = tid & 3;
  for (int kt = 0; kt < 7; ++kt) {
    if (kt) __syncthreads();
    #pragma unroll
    for (int it = 0; it < 3; ++it) {
      const int row = it * 64 + srow;
      *(uint4*)(sAs + row * 40 + sj * 8) =
          *(const uint4*)(AT + (size_t)(vc0 + row) * KPAD + kt * 32 + sj * 8);
    }
    *(uint4*)(sBs + srow * 40 + sj * 8) =
        *(const uint4*)(BT + (size_t)(b0 + srow) * KPAD + kt * 32 + sj * 8);
    __syncthreads();
    short8 af[3], bfr[4];
    #pragma unroll
    for (int mt = 0; mt < 3; ++mt)
      af[mt] = *(const short8*)(sAs + (48 * wv + 16 * mt + n) * 40 + q * 8);
    #pragma unroll
    for (int nt = 0; nt < 4; ++nt)
      bfr[nt] = *(const short8*)(sBs + (16 * nt + n) * 40 + q * 8);
    #pragma unroll
    for (int mt = 0; mt < 3; ++mt)
      #pragma unroll
      for (int nt = 0; nt < 4; ++nt)
        acc[mt][nt] = __builtin_amdgcn_mfma_f32_16x16x32_bf16(
            af[mt], bfr[nt], acc[mt][nt], 0, 0, 0);
  }

  short8 wh[4], wl[4];
  #pragma unroll
  for (int vt = 0; vt < 4; ++vt) {
    wh[vt] = *(const short8*)(sWh + (vt * 16 + n) * 40 + q * 8);
    wl[vt] = *(const short8*)(sWl + (vt * 16 + n) * 40 + q * 8);
  }

  for (int nt = 0; nt < 4; ++nt) {
    for (int s = 0; s < 2; ++s) {
      __syncthreads();
      if (s == 0) {
        #pragma unroll
        for (int mt = 0; mt < 3; ++mt)
          #pragma unroll
          for (int r = 0; r < 4; ++r)
            sV[(48 * wv + 16 * mt + 4 * q + r) * 17 + n] = acc[mt][nt][r];
      }
      const int bg0 = b0 + nt * 16 + s * 8;
      for (int i = tid; i < 1024; i += 256) {
        const int row = i >> 2, c4 = i & 3;
        const int t = row >> 5, rem = row & 31;
        *(uint4*)(sG2 + row * 40 + c4 * 8) =
            *(const uint4*)(G16 + (size_t)(bg0 + t) * 1024 + rem * 32 + c4 * 8);
      }
      __syncthreads();
      #pragma unroll
      for (int bb = 0; bb < 2; ++bb) {
        const int t = wv * 2 + bb;
        const int col = s * 8 + t;
        const int bg = b0 + nt * 16 + col;
        const short8 gh = *(const short8*)(sG2 + (t * 32 + n) * 40 + q * 8);
        const short8 gl = *(const short8*)(sG2 + (t * 32 + 16 + n) * 40 + q * 8);
        #pragma unroll
        for (int vt = 0; vt < 4; ++vt) {
          floatx4 a2 = (floatx4)(0.f);
          a2 = __builtin_amdgcn_mfma_f32_16x16x32_bf16(gh, wl[vt], a2, 0, 0, 0);
          a2 = __builtin_amdgcn_mfma_f32_16x16x32_bf16(gl, wh[vt], a2, 0, 0, 0);
          a2 = __builtin_amdgcn_mfma_f32_16x16x32_bf16(gh, wh[vt], a2, 0, 0, 0);
          const float X = sV[(48 * vt + 3 * n + 0) * 17 + col];
          const float Y = sV[(48 * vt + 3 * n + 1) * 17 + col];
          const float Z = sV[(48 * vt + 3 * n + 2) * 17 + col];
          const float o = a2[0] * X + a2[1] * Y + a2[2] * Z + a2[3];
          const int vc = vc0 + 48 * vt + 3 * n + q;
          if (q < 3 && vc < NVC)
            out[(size_t)bg * NVC + vc] = o;
        }
      }
    }
  }
}

// ---- joints = Jr @ result ----
__global__ __launch_bounds__(256) void k_joints(
    const float* __restrict__ Jr, const float* __restrict__ res,
    float* __restrict__ joints) {
  const int b = blockIdx.x;
  const int lane = threadIdx.x & 63, wv = threadIdx.x >> 6;
  float acc[18];
  #pragma unroll
  for (int k = 0; k < 18; ++k) acc[k] = 0.f;
  const float* rb = res + (size_t)b * NVC;
  for (int v = lane; v < NVERT; v += 64) {
    const float r0 = rb[v*3+0], r1 = rb[v*3+1], r2 = rb[v*3+2];
    #pragma unroll
    for (int k = 0; k < 6; ++k) {
      const int j = wv + 4 * k;
      const float w = Jr[j * NVERT + v];
      acc[k*3+0] += w * r0; acc[k*3+1] += w * r1; acc[k*3+2] += w * r2;
    }
  }
  #pragma unroll
  for (int off = 32; off > 0; off >>= 1) {
    #pragma unroll
    for (int k = 0; k < 18; ++k) acc[k] += __shfl_down(acc[k], off, 64);
  }
  if (lane == 0) {
    #pragma unroll
    for (int k = 0; k < 6; ++k) {
      const int j = wv + 4 * k;
      joints[(size_t)b * 72 + j * 3 + 0] = acc[k*3+0];
      joints[(size_t)b * 72 + j * 3 + 1] = acc[k*3+1];
      joints[(size_t)b * 72 + j * 3 + 2] = acc[k*3+2];
    }
  }
}

extern "C" void kernel_launch(void* const* d_in, const int* in_sizes, int n_in,
                              void* d_out, int out_size, void* d_ws, size_t ws_size,
                              hipStream_t stream) {
  const float* betas  = (const float*)d_in[0];
  const float* thetas = (const float*)d_in[1];
  const float* trans  = (const float*)d_in[2];
  const float* scale  = (const float*)d_in[3];
  const float* vtpl   = (const float*)d_in[4];
  const float* sd     = (const float*)d_in[5];
  const float* pdir   = (const float*)d_in[6];
  const float* Jr     = (const float*)d_in[7];
  const float* wgt    = (const float*)d_in[8];
  float* out = (float*)d_out;

  float* ws   = (float*)d_ws;
  float* wsJP = ws;                                          // 6336 floats
  unsigned short* AT  = (unsigned short*)(ws + 6336);        // MROWS*224
  unsigned short* BT  = AT + (size_t)MROWS * KPAD;           // 512*224
  unsigned short* W16 = BT + (size_t)NBATCH * KPAD;          // 6912*64
  unsigned short* G16 = W16 + (size_t)6912 * 64;             // 512*1024

  k_buildA<<<(MROWS * KPAD) / 256, 256, 0, stream>>>(pdir, sd, vtpl, AT);
  k_buildW<<<(6912 * 64) / 256, 256, 0, stream>>>(wgt, W16);
  k_jreg1<<<dim3(72, 8), 256, 0, stream>>>(Jr, vtpl, sd, wsJP);
  k_chain3<<<NBATCH / 4, 256, 0, stream>>>(betas, thetas, scale, trans, wsJP, BT, G16);
  k_skin4<<<dim3(8, 108), 256, 0, stream>>>(AT, BT, W16, G16, out);
  k_joints<<<NBATCH, 256, 0, stream>>>(Jr, out, out + (size_t)NBATCH * NVC);
}